// Round 3
// baseline (572.101 us; speedup 1.0000x reference)
//
#include <hip/hip_runtime.h>
#include <math.h>

#define F 64
#define NPB 160        // nodes per bucket
#define STAGE_CAP 6304 // staged CSR entries per bucket (mean ~2720, +60 sigma)

// ---------------- bucketed CSR build ----------------

__global__ __launch_bounds__(256) void k_bin_count(const int* __restrict__ edst, int* __restrict__ cntT,
                                                   int e, int ch, int nblk, int nb) {
  __shared__ int h[1024];
  int k = blockIdx.x, tid = threadIdx.x;
  for (int i = tid; i < nb; i += 256) h[i] = 0;
  __syncthreads();
  int beg = k * ch, end = min(e, beg + ch);
  for (int i = beg + tid; i < end; i += 256) atomicAdd(&h[edst[i] / NPB], 1);
  __syncthreads();
  for (int b = tid; b < nb; b += 256) cntT[b * nblk + k] = h[b];
}

__global__ __launch_bounds__(256) void k_scan1(const int* __restrict__ counts, int* __restrict__ offs,
                                               int* __restrict__ bsums, int n) {
  int tid = threadIdx.x, lane = tid & 63, wv = tid >> 6;
  int i = blockIdx.x * 256 + tid;
  int v = (i < n) ? counts[i] : 0;
  int x = v;
  #pragma unroll
  for (int o = 1; o <= 32; o <<= 1) { int y = __shfl_up(x, o); if (lane >= o) x += y; }
  __shared__ int wsum[4];
  if (lane == 63) wsum[wv] = x;
  __syncthreads();
  int add = 0;
  for (int w = 0; w < wv; w++) add += wsum[w];
  int incl = x + add;
  if (i < n) offs[i] = incl - v;
  if (tid == 255) bsums[blockIdx.x] = incl;
}

__global__ __launch_bounds__(256) void k_scan2(int* __restrict__ bs, int nb) {
  __shared__ int wsum[4];
  __shared__ int carry_sh;
  int tid = threadIdx.x, lane = tid & 63, wv = tid >> 6;
  if (tid == 0) carry_sh = 0;
  __syncthreads();
  for (int base = 0; base < nb; base += 256) {
    int i = base + tid;
    int v = (i < nb) ? bs[i] : 0;
    int x = v;
    #pragma unroll
    for (int o = 1; o <= 32; o <<= 1) { int y = __shfl_up(x, o); if (lane >= o) x += y; }
    if (lane == 63) wsum[wv] = x;
    __syncthreads();
    int add = 0;
    for (int w = 0; w < wv; w++) add += wsum[w];
    int incl = x + add;
    int carry = carry_sh;
    if (i < nb) bs[i] = incl - v + carry;
    __syncthreads();
    if (tid == 255) carry_sh = carry + incl;
    __syncthreads();
  }
}

__global__ __launch_bounds__(256) void k_scan3(int* __restrict__ offs, const int* __restrict__ bsums,
                                               int n, int total) {
  int i = blockIdx.x * 256 + threadIdx.x;
  if (i < n) offs[i] += bsums[i >> 8];
  if (i == 0) offs[n] = total;
}

__global__ __launch_bounds__(256) void k_bin_scatter(const int* __restrict__ esrc, const int* __restrict__ edst,
                                                     const int* __restrict__ posT, unsigned int* __restrict__ binned,
                                                     int e, int ch, int nblk, int nb) {
  __shared__ int cur[1024];
  int k = blockIdx.x, tid = threadIdx.x;
  for (int b = tid; b < nb; b += 256) cur[b] = posT[b * nblk + k];
  __syncthreads();
  int beg = k * ch, end = min(e, beg + ch);
  for (int i = beg + tid; i < end; i += 256) {
    int d = edst[i];
    int b = d / NPB;
    unsigned int ld = (unsigned int)(d - b * NPB);
    int p = atomicAdd(&cur[b], 1);
    binned[p] = (unsigned int)esrc[i] | (ld << 24);
  }
}

// one block per bucket: build CSR rows (self-loop at row head), emit pk.x=src, offs
__global__ __launch_bounds__(256) void k_bucket_csr(const unsigned int* __restrict__ binned,
                                                    const int* __restrict__ posT,
                                                    int2* __restrict__ pk, int* __restrict__ offs,
                                                    int n, int nblk, int nb, int e) {
  __shared__ int ncnt[NPB];
  __shared__ int noff[NPB];
  __shared__ int cur[NPB];
  __shared__ int sc[256];
  __shared__ int stage[STAGE_CAP];
  int b = blockIdx.x, tid = threadIdx.x;
  int node0 = b * NPB;
  int nn = min(NPB, n - node0);
  int ebeg = posT[b * nblk];
  int eend = posT[(b + 1) * nblk];
  int ecnt = eend - ebeg;
  for (int i = tid; i < NPB; i += 256) ncnt[i] = 0;
  __syncthreads();
  for (int i = tid; i < ecnt; i += 256) { unsigned int v = binned[ebeg + i]; atomicAdd(&ncnt[v >> 24], 1); }
  __syncthreads();
  int x = (tid < nn) ? ncnt[tid] + 1 : 0;
  sc[tid] = x;
  __syncthreads();
  #pragma unroll
  for (int o = 1; o < 256; o <<= 1) {
    int y = (tid >= o) ? sc[tid - o] : 0;
    __syncthreads();
    sc[tid] += y;
    __syncthreads();
  }
  if (tid < nn) noff[tid] = sc[tid] - x;
  __syncthreads();
  int tot = ecnt + nn;
  int outbase = ebeg + node0;
  bool staged = (tot <= STAGE_CAP);
  if (tid < nn) {
    cur[tid] = noff[tid] + 1;
    offs[node0 + tid] = outbase + noff[tid];
    if (staged) stage[noff[tid]] = node0 + tid;
    else        pk[outbase + noff[tid]] = make_int2(node0 + tid, 0);
  }
  __syncthreads();
  if (staged) {
    for (int i = tid; i < ecnt; i += 256) {
      unsigned int v = binned[ebeg + i];
      int p = atomicAdd(&cur[v >> 24], 1);
      stage[p] = (int)(v & 0xFFFFFFu);
    }
    __syncthreads();
    for (int i = tid; i < tot; i += 256) pk[outbase + i] = make_int2(stage[i], 0);
  } else {
    for (int i = tid; i < ecnt; i += 256) {
      unsigned int v = binned[ebeg + i];
      int p = atomicAdd(&cur[v >> 24], 1);
      pk[outbase + p] = make_int2((int)(v & 0xFFFFFFu), 0);
    }
  }
  if (b == 0 && tid == 0) offs[n] = e + n;
}

// ---------------- GEMM h = in @ W (64x64), fused al_src/al_dst ----------------
__global__ __launch_bounds__(256) void k_gemm(const float* __restrict__ in, const float* __restrict__ W,
                                              const float* __restrict__ avs, const float* __restrict__ avd,
                                              float* __restrict__ hg, float* __restrict__ als,
                                              float* __restrict__ ald, int n) {
  __shared__ float4 Xsh[64 * 16];
  int tid = threadIdx.x, lane = tid & 63, wv = tid >> 6;
  float wreg[F];
  #pragma unroll
  for (int k = 0; k < F; k++) wreg[k] = W[k * F + lane];
  float as = avs[lane], ad = avd[lane];
  const float4* in4 = (const float4*)in;
  int nchunks = n >> 6;
  for (int chunk = blockIdx.x; chunk < nchunks; chunk += gridDim.x) {
    int r0 = chunk << 6;
    __syncthreads();
    #pragma unroll
    for (int i = 0; i < 4; i++) Xsh[i * 256 + tid] = in4[(size_t)r0 * 16 + i * 256 + tid];
    __syncthreads();
    int rl0 = wv * 16;
    for (int rl = rl0; rl < rl0 + 16; rl++) {
      float acc = 0.f;
      #pragma unroll
      for (int k4 = 0; k4 < 16; k4++) {
        float4 xk = Xsh[rl * 16 + k4];
        acc = fmaf(xk.x, wreg[k4 * 4 + 0], acc);
        acc = fmaf(xk.y, wreg[k4 * 4 + 1], acc);
        acc = fmaf(xk.z, wreg[k4 * 4 + 2], acc);
        acc = fmaf(xk.w, wreg[k4 * 4 + 3], acc);
      }
      int r = r0 + rl;
      hg[(size_t)r * F + lane] = acc;
      float ps = acc * as, pd = acc * ad;
      #pragma unroll
      for (int o = 32; o >= 1; o >>= 1) { ps += __shfl_xor(ps, o); pd += __shfl_xor(pd, o); }
      if (lane == 0) { als[r] = ps; ald[r] = pd; }
    }
  }
}

// ---------------- alpha pass: pk.y = exp(leaky(als[src]+ald[node])), inv = 1/sum ----------------
// 16-lane group per node, 16 nodes per block
__global__ __launch_bounds__(256) void k_alpha(const int* __restrict__ offs, int2* __restrict__ pk,
                                               const float* __restrict__ als, const float* __restrict__ ald,
                                               float* __restrict__ inv, int n) {
  int tid = threadIdx.x, lq = tid & 15, grp = tid >> 4;
  int node = blockIdx.x * 16 + grp;
  if (node >= n) return;
  int beg = offs[node], end = offs[node + 1];
  float aldv = ald[node];
  float ssum = 0.f;
  for (int c = beg + lq; c < end; c += 16) {
    int src = pk[c].x;
    float t = als[src] + aldv;
    float e = (t >= 0.f) ? t : 0.2f * t;
    float ex = __expf(e);
    pk[c] = make_int2(src, __float_as_int(ex));
    ssum += ex;
  }
  #pragma unroll
  for (int o = 1; o <= 8; o <<= 1) ssum += __shfl_xor(ssum, o);
  if (lq == 0) inv[node] = 1.f / (ssum + 1e-16f);
}

// ---------------- SpMM: out[node] = relu(inv * sum_e ex_e * h[src_e] + bias) ----------------
// wave per node; 4 groups of 16 lanes; group g handles edges j = 4*j4+g; 16 lanes x float4 per row
__global__ __launch_bounds__(256) void k_spmm(const int* __restrict__ offs, const int2* __restrict__ pk,
                                              const float* __restrict__ hg, const float* __restrict__ inv,
                                              const float* __restrict__ bias, float* __restrict__ outp, int n) {
  int tid = threadIdx.x, lane = tid & 63, wv = tid >> 6;
  int grp = lane >> 4, lq = lane & 15;
  int node = blockIdx.x * 4 + wv;
  if (node >= n) return;
  const float4* hg4 = (const float4*)hg;
  float4 b4 = ((const float4*)bias)[lq];
  int beg = offs[node], end = offs[node + 1];
  int deg = end - beg;
  float4 acc = make_float4(0.f, 0.f, 0.f, 0.f);
  int iters = (deg + 3) >> 2;
  #pragma unroll 2
  for (int j4 = 0; j4 < iters; j4++) {
    int j = (j4 << 2) + grp;
    bool valid = j < deg;
    int pos = valid ? (beg + j) : beg;   // slot beg (self-loop) always exists
    int2 pv = pk[pos];
    float w = valid ? __int_as_float(pv.y) : 0.f;
    float4 hrow = hg4[(size_t)pv.x * 16 + lq];
    acc.x = fmaf(w, hrow.x, acc.x);
    acc.y = fmaf(w, hrow.y, acc.y);
    acc.z = fmaf(w, hrow.z, acc.z);
    acc.w = fmaf(w, hrow.w, acc.w);
  }
  #pragma unroll
  for (int o = 16; o <= 32; o <<= 1) {
    acc.x += __shfl_xor(acc.x, o);
    acc.y += __shfl_xor(acc.y, o);
    acc.z += __shfl_xor(acc.z, o);
    acc.w += __shfl_xor(acc.w, o);
  }
  if (lane < 16) {
    float iv = inv[node];
    float4 r;
    r.x = fmaxf(fmaf(acc.x, iv, b4.x), 0.f);
    r.y = fmaxf(fmaf(acc.y, iv, b4.y), 0.f);
    r.z = fmaxf(fmaf(acc.z, iv, b4.z), 0.f);
    r.w = fmaxf(fmaf(acc.w, iv, b4.w), 0.f);
    ((float4*)outp)[(size_t)node * 16 + lq] = r;
  }
}

// ---------------- final readout ----------------
__global__ __launch_bounds__(256) void k_final(const float* __restrict__ h, const float* __restrict__ Wout,
                                               const float* __restrict__ bout, float* __restrict__ out,
                                               int ng) {
  int tid = threadIdx.x, lane = tid & 63, wv = tid >> 6;
  int g = blockIdx.x * 4 + wv;
  if (g >= ng) return;
  const float4* h4 = (const float4*)h + (size_t)g * 320;
  const float4* w4 = (const float4*)Wout;
  float sacc = 0.f;
  #pragma unroll
  for (int k = 0; k < 5; k++) {
    float4 a = h4[k * 64 + lane];
    float4 b = w4[k * 64 + lane];
    sacc += a.x * b.x + a.y * b.y + a.z * b.z + a.w * b.w;
  }
  #pragma unroll
  for (int o = 32; o >= 1; o >>= 1) sacc += __shfl_xor(sacc, o);
  if (lane == 0) out[g] = sacc + bout[0];
}

// ---------------- launch ----------------
extern "C" void kernel_launch(void* const* d_in, const int* in_sizes, int n_in,
                              void* d_out, int out_size, void* d_ws, size_t ws_size,
                              hipStream_t stream) {
  const float* x   = (const float*)d_in[0];
  const int*   ei  = (const int*)d_in[1];
  const float* W1  = (const float*)d_in[2];
  const float* as1 = (const float*)d_in[3];
  const float* ad1 = (const float*)d_in[4];
  const float* b1  = (const float*)d_in[5];
  const float* W2  = (const float*)d_in[6];
  const float* as2 = (const float*)d_in[7];
  const float* ad2 = (const float*)d_in[8];
  const float* b2  = (const float*)d_in[9];
  const float* Wo  = (const float*)d_in[10];
  const float* bo  = (const float*)d_in[11];
  float* out = (float*)d_out;

  const int N = in_sizes[0] / F;
  const int E = in_sizes[1] / 2;
  const int* esrc = ei;
  const int* edst = ei + E;

  size_t off = 0;
  auto alloc = [&](size_t bytes) -> void* {
    void* p = (char*)d_ws + off;
    off += (bytes + 255) & ~(size_t)255;
    return p;
  };
  float* A    = (float*)alloc((size_t)N * F * 4);   // agg outputs; CSR count/pos scratch aliases head
  float* B    = (float*)alloc((size_t)N * F * 4);   // gemm outputs; binned[] aliases head
  float* als  = (float*)alloc((size_t)N * 4);
  float* ald  = (float*)alloc((size_t)N * 4);
  int* offs   = (int*)alloc((size_t)(N + 1) * 4);
  int* bsums  = (int*)alloc(8192);
  float* inv  = (float*)alloc((size_t)N * 4);
  int2* pk    = (int2*)alloc((size_t)(E + N) * 8);  // (src, ex) per CSR slot
  (void)ws_size; (void)n_in; (void)out_size;

  const int NBLK = 160;
  const int NB = (N + NPB - 1) / NPB;
  const int CH = (E + NBLK - 1) / NBLK;
  const int FLAT = NB * NBLK;

  int* cntT = (int*)A;
  int* posT = (int*)((char*)A + ((size_t)FLAT * 4 + 1024));
  unsigned int* binned = (unsigned int*)B;

  int gF = (FLAT + 255) / 256;

  // CSR build: bucketed counting sort (dst-major), self-loop at row head
  k_bin_count<<<NBLK, 256, 0, stream>>>(edst, cntT, E, CH, NBLK, NB);
  k_scan1<<<gF, 256, 0, stream>>>(cntT, posT, bsums, FLAT);
  k_scan2<<<1, 256, 0, stream>>>(bsums, gF);
  k_scan3<<<gF, 256, 0, stream>>>(posT, bsums, FLAT, E);
  k_bin_scatter<<<NBLK, 256, 0, stream>>>(esrc, edst, posT, binned, E, CH, NBLK, NB);
  k_bucket_csr<<<NB, 256, 0, stream>>>(binned, posT, pk, offs, N, NBLK, NB, E);

  int gAl = (N + 15) / 16;
  int gSp = (N + 3) / 4;
  // layer 1
  k_gemm<<<640, 256, 0, stream>>>(x, W1, as1, ad1, B, als, ald, N);
  k_alpha<<<gAl, 256, 0, stream>>>(offs, pk, als, ald, inv, N);
  k_spmm<<<gSp, 256, 0, stream>>>(offs, pk, B, inv, b1, A, N);
  // layer 2
  k_gemm<<<640, 256, 0, stream>>>(A, W2, as2, ad2, B, als, ald, N);
  k_alpha<<<gAl, 256, 0, stream>>>(offs, pk, als, ald, inv, N);
  k_spmm<<<gSp, 256, 0, stream>>>(offs, pk, B, inv, b2, A, N);
  // readout
  int NG = N / 20;
  k_final<<<(NG + 3) / 4, 256, 0, stream>>>(A, Wo, bo, out, NG);
}

// Round 4
// 524.878 us; speedup vs baseline: 1.0900x; 1.0900x over previous
//
#include <hip/hip_runtime.h>
#include <math.h>

#define F 64
#define NPB 160        // nodes per bucket
#define STAGE_CAP 6304 // staged CSR entries per bucket (mean ~2720, +60 sigma)

// ---------------- bucketed CSR build ----------------

__global__ __launch_bounds__(256) void k_bin_count(const int* __restrict__ edst, int* __restrict__ cntT,
                                                   int e, int ch, int nblk, int nb) {
  __shared__ int h[1024];
  int k = blockIdx.x, tid = threadIdx.x;
  for (int i = tid; i < nb; i += 256) h[i] = 0;
  __syncthreads();
  int beg = k * ch, end = min(e, beg + ch);
  for (int i = beg + tid; i < end; i += 256) atomicAdd(&h[edst[i] / NPB], 1);
  __syncthreads();
  for (int b = tid; b < nb; b += 256) cntT[b * nblk + k] = h[b];
}

__global__ __launch_bounds__(256) void k_scan1(const int* __restrict__ counts, int* __restrict__ offs,
                                               int* __restrict__ bsums, int n) {
  int tid = threadIdx.x, lane = tid & 63, wv = tid >> 6;
  int i = blockIdx.x * 256 + tid;
  int v = (i < n) ? counts[i] : 0;
  int x = v;
  #pragma unroll
  for (int o = 1; o <= 32; o <<= 1) { int y = __shfl_up(x, o); if (lane >= o) x += y; }
  __shared__ int wsum[4];
  if (lane == 63) wsum[wv] = x;
  __syncthreads();
  int add = 0;
  for (int w = 0; w < wv; w++) add += wsum[w];
  int incl = x + add;
  if (i < n) offs[i] = incl - v;
  if (tid == 255) bsums[blockIdx.x] = incl;
}

__global__ __launch_bounds__(256) void k_scan2(int* __restrict__ bs, int nb) {
  __shared__ int wsum[4];
  __shared__ int carry_sh;
  int tid = threadIdx.x, lane = tid & 63, wv = tid >> 6;
  if (tid == 0) carry_sh = 0;
  __syncthreads();
  for (int base = 0; base < nb; base += 256) {
    int i = base + tid;
    int v = (i < nb) ? bs[i] : 0;
    int x = v;
    #pragma unroll
    for (int o = 1; o <= 32; o <<= 1) { int y = __shfl_up(x, o); if (lane >= o) x += y; }
    if (lane == 63) wsum[wv] = x;
    __syncthreads();
    int add = 0;
    for (int w = 0; w < wv; w++) add += wsum[w];
    int incl = x + add;
    int carry = carry_sh;
    if (i < nb) bs[i] = incl - v + carry;
    __syncthreads();
    if (tid == 255) carry_sh = carry + incl;
    __syncthreads();
  }
}

__global__ __launch_bounds__(256) void k_scan3(int* __restrict__ offs, const int* __restrict__ bsums,
                                               int n, int total) {
  int i = blockIdx.x * 256 + threadIdx.x;
  if (i < n) offs[i] += bsums[i >> 8];
  if (i == 0) offs[n] = total;
}

__global__ __launch_bounds__(256) void k_bin_scatter(const int* __restrict__ esrc, const int* __restrict__ edst,
                                                     const int* __restrict__ posT, unsigned int* __restrict__ binned,
                                                     int e, int ch, int nblk, int nb) {
  __shared__ int cur[1024];
  int k = blockIdx.x, tid = threadIdx.x;
  for (int b = tid; b < nb; b += 256) cur[b] = posT[b * nblk + k];
  __syncthreads();
  int beg = k * ch, end = min(e, beg + ch);
  for (int i = beg + tid; i < end; i += 256) {
    int d = edst[i];
    int b = d / NPB;
    unsigned int ld = (unsigned int)(d - b * NPB);
    int p = atomicAdd(&cur[b], 1);
    binned[p] = (unsigned int)esrc[i] | (ld << 24);
  }
}

// one block per bucket: build CSR rows (self-loop at row head), emit ssrc + offs
__global__ __launch_bounds__(256) void k_bucket_csr(const unsigned int* __restrict__ binned,
                                                    const int* __restrict__ posT,
                                                    int* __restrict__ ssrc, int* __restrict__ offs,
                                                    int n, int nblk, int nb, int e) {
  __shared__ int ncnt[NPB];
  __shared__ int noff[NPB];
  __shared__ int cur[NPB];
  __shared__ int sc[256];
  __shared__ int stage[STAGE_CAP];
  int b = blockIdx.x, tid = threadIdx.x;
  int node0 = b * NPB;
  int nn = min(NPB, n - node0);
  int ebeg = posT[b * nblk];
  int eend = posT[(b + 1) * nblk];
  int ecnt = eend - ebeg;
  for (int i = tid; i < NPB; i += 256) ncnt[i] = 0;
  __syncthreads();
  for (int i = tid; i < ecnt; i += 256) { unsigned int v = binned[ebeg + i]; atomicAdd(&ncnt[v >> 24], 1); }
  __syncthreads();
  int x = (tid < nn) ? ncnt[tid] + 1 : 0;
  sc[tid] = x;
  __syncthreads();
  #pragma unroll
  for (int o = 1; o < 256; o <<= 1) {
    int y = (tid >= o) ? sc[tid - o] : 0;
    __syncthreads();
    sc[tid] += y;
    __syncthreads();
  }
  if (tid < nn) noff[tid] = sc[tid] - x;
  __syncthreads();
  int tot = ecnt + nn;
  int outbase = ebeg + node0;
  bool staged = (tot <= STAGE_CAP);
  if (tid < nn) {
    cur[tid] = noff[tid] + 1;
    offs[node0 + tid] = outbase + noff[tid];
    if (staged) stage[noff[tid]] = node0 + tid;
    else        ssrc[outbase + noff[tid]] = node0 + tid;
  }
  __syncthreads();
  if (staged) {
    for (int i = tid; i < ecnt; i += 256) {
      unsigned int v = binned[ebeg + i];
      int p = atomicAdd(&cur[v >> 24], 1);
      stage[p] = (int)(v & 0xFFFFFFu);
    }
    __syncthreads();
    for (int i = tid; i < tot; i += 256) ssrc[outbase + i] = stage[i];
  } else {
    for (int i = tid; i < ecnt; i += 256) {
      unsigned int v = binned[ebeg + i];
      int p = atomicAdd(&cur[v >> 24], 1);
      ssrc[outbase + p] = (int)(v & 0xFFFFFFu);
    }
  }
  if (b == 0 && tid == 0) offs[n] = e + n;
}

// ---------------- GEMM h = in @ W (64x64): bf16 h out, fp32 al_src/al_dst ----------------
__global__ __launch_bounds__(256) void k_gemm(const float* __restrict__ in, const float* __restrict__ W,
                                              const float* __restrict__ avs, const float* __restrict__ avd,
                                              unsigned short* __restrict__ hgb, float* __restrict__ als,
                                              float* __restrict__ ald, int n) {
  __shared__ float4 Xsh[64 * 16];
  int tid = threadIdx.x, lane = tid & 63, wv = tid >> 6;
  float wreg[F];
  #pragma unroll
  for (int k = 0; k < F; k++) wreg[k] = W[k * F + lane];
  float as = avs[lane], ad = avd[lane];
  const float4* in4 = (const float4*)in;
  int nchunks = n >> 6;
  for (int chunk = blockIdx.x; chunk < nchunks; chunk += gridDim.x) {
    int r0 = chunk << 6;
    __syncthreads();
    #pragma unroll
    for (int i = 0; i < 4; i++) Xsh[i * 256 + tid] = in4[(size_t)r0 * 16 + i * 256 + tid];
    __syncthreads();
    int rl0 = wv * 16;
    for (int rl = rl0; rl < rl0 + 16; rl++) {
      float acc = 0.f;
      #pragma unroll
      for (int k4 = 0; k4 < 16; k4++) {
        float4 xk = Xsh[rl * 16 + k4];
        acc = fmaf(xk.x, wreg[k4 * 4 + 0], acc);
        acc = fmaf(xk.y, wreg[k4 * 4 + 1], acc);
        acc = fmaf(xk.z, wreg[k4 * 4 + 2], acc);
        acc = fmaf(xk.w, wreg[k4 * 4 + 3], acc);
      }
      int r = r0 + rl;
      // bf16 round-to-nearest-even
      unsigned int u = __float_as_uint(acc);
      u += 0x7fffu + ((u >> 16) & 1u);
      hgb[(size_t)r * F + lane] = (unsigned short)(u >> 16);
      float ps = acc * as, pd = acc * ad;
      #pragma unroll
      for (int o = 32; o >= 1; o >>= 1) { ps += __shfl_xor(ps, o); pd += __shfl_xor(pd, o); }
      if (lane == 0) { als[r] = ps; ald[r] = pd; }
    }
  }
}

// ---------------- fused softmax+SpMM: out = relu( (Σ ex_e·h[src_e]) / Σ ex_e + bias ) ----------------
// wave per node; 4 groups of 16 lanes; group g handles edges j = 4*j4+g; 16 lanes x 4 bf16 per row
__global__ __launch_bounds__(256) void k_spmm(const int* __restrict__ offs, const int* __restrict__ ssrc,
                                              const unsigned short* __restrict__ hgb,
                                              const float* __restrict__ als, const float* __restrict__ ald,
                                              const float* __restrict__ bias, float* __restrict__ outp, int n) {
  int tid = threadIdx.x, lane = tid & 63, wv = tid >> 6;
  int grp = lane >> 4, lq = lane & 15;
  int node = blockIdx.x * 4 + wv;
  if (node >= n) return;
  const uint2* hg2 = (const uint2*)hgb;  // row = 16 x uint2 (4 bf16 each)
  float4 b4 = ((const float4*)bias)[lq];
  int beg = offs[node], end = offs[node + 1];
  int deg = end - beg;
  float aldv = ald[node];
  float4 acc = make_float4(0.f, 0.f, 0.f, 0.f);
  float s = 0.f;
  int iters = (deg + 3) >> 2;
  #pragma unroll 2
  for (int j4 = 0; j4 < iters; j4++) {
    int j = (j4 << 2) + grp;
    bool valid = j < deg;
    int pos = valid ? (beg + j) : beg;   // slot beg (self-loop) always exists
    int src = ssrc[pos];
    float t = als[src] + aldv;
    t = (t >= 0.f) ? t : 0.2f * t;       // leaky_relu 0.2
    float ex = valid ? __expf(t) : 0.f;
    uint2 u = hg2[(size_t)src * 16 + lq];
    float c0 = __uint_as_float(u.x << 16);
    float c1 = __uint_as_float(u.x & 0xffff0000u);
    float c2 = __uint_as_float(u.y << 16);
    float c3 = __uint_as_float(u.y & 0xffff0000u);
    acc.x = fmaf(ex, c0, acc.x);
    acc.y = fmaf(ex, c1, acc.y);
    acc.z = fmaf(ex, c2, acc.z);
    acc.w = fmaf(ex, c3, acc.w);
    s += ex;
  }
  #pragma unroll
  for (int o = 16; o <= 32; o <<= 1) {
    acc.x += __shfl_xor(acc.x, o);
    acc.y += __shfl_xor(acc.y, o);
    acc.z += __shfl_xor(acc.z, o);
    acc.w += __shfl_xor(acc.w, o);
    s     += __shfl_xor(s, o);
  }
  if (lane < 16) {
    float iv = 1.f / (s + 1e-16f);
    float4 r;
    r.x = fmaxf(fmaf(acc.x, iv, b4.x), 0.f);
    r.y = fmaxf(fmaf(acc.y, iv, b4.y), 0.f);
    r.z = fmaxf(fmaf(acc.z, iv, b4.z), 0.f);
    r.w = fmaxf(fmaf(acc.w, iv, b4.w), 0.f);
    ((float4*)outp)[(size_t)node * 16 + lq] = r;
  }
}

// ---------------- final readout ----------------
__global__ __launch_bounds__(256) void k_final(const float* __restrict__ h, const float* __restrict__ Wout,
                                               const float* __restrict__ bout, float* __restrict__ out,
                                               int ng) {
  int tid = threadIdx.x, lane = tid & 63, wv = tid >> 6;
  int g = blockIdx.x * 4 + wv;
  if (g >= ng) return;
  const float4* h4 = (const float4*)h + (size_t)g * 320;
  const float4* w4 = (const float4*)Wout;
  float sacc = 0.f;
  #pragma unroll
  for (int k = 0; k < 5; k++) {
    float4 a = h4[k * 64 + lane];
    float4 b = w4[k * 64 + lane];
    sacc += a.x * b.x + a.y * b.y + a.z * b.z + a.w * b.w;
  }
  #pragma unroll
  for (int o = 32; o >= 1; o >>= 1) sacc += __shfl_xor(sacc, o);
  if (lane == 0) out[g] = sacc + bout[0];
}

// ---------------- launch ----------------
extern "C" void kernel_launch(void* const* d_in, const int* in_sizes, int n_in,
                              void* d_out, int out_size, void* d_ws, size_t ws_size,
                              hipStream_t stream) {
  const float* x   = (const float*)d_in[0];
  const int*   ei  = (const int*)d_in[1];
  const float* W1  = (const float*)d_in[2];
  const float* as1 = (const float*)d_in[3];
  const float* ad1 = (const float*)d_in[4];
  const float* b1  = (const float*)d_in[5];
  const float* W2  = (const float*)d_in[6];
  const float* as2 = (const float*)d_in[7];
  const float* ad2 = (const float*)d_in[8];
  const float* b2  = (const float*)d_in[9];
  const float* Wo  = (const float*)d_in[10];
  const float* bo  = (const float*)d_in[11];
  float* out = (float*)d_out;

  const int N = in_sizes[0] / F;
  const int E = in_sizes[1] / 2;
  const int* esrc = ei;
  const int* edst = ei + E;

  size_t off = 0;
  auto alloc = [&](size_t bytes) -> void* {
    void* p = (char*)d_ws + off;
    off += (bytes + 255) & ~(size_t)255;
    return p;
  };
  float* A    = (float*)alloc((size_t)N * F * 4);           // agg outputs (fp32); CSR cnt/pos scratch aliases head
  unsigned short* hgb = (unsigned short*)alloc((size_t)N * F * 2);  // bf16 gemm outputs; binned aliases head
  float* als  = (float*)alloc((size_t)N * 4);
  float* ald  = (float*)alloc((size_t)N * 4);
  int* offs   = (int*)alloc((size_t)(N + 1) * 4);
  int* bsums  = (int*)alloc(8192);
  int* ssrc   = (int*)alloc((size_t)(E + N) * 4);           // CSR src lists
  (void)ws_size; (void)n_in; (void)out_size;

  const int NBLK = 160;
  const int NB = (N + NPB - 1) / NPB;
  const int CH = (E + NBLK - 1) / NBLK;
  const int FLAT = NB * NBLK;

  int* cntT = (int*)A;
  int* posT = (int*)((char*)A + ((size_t)FLAT * 4 + 1024));
  unsigned int* binned = (unsigned int*)hgb;   // E uints <= N*F*2 bytes; dead before k_gemm writes hgb

  int gF = (FLAT + 255) / 256;

  // CSR build: bucketed counting sort (dst-major), self-loop at row head
  k_bin_count<<<NBLK, 256, 0, stream>>>(edst, cntT, E, CH, NBLK, NB);
  k_scan1<<<gF, 256, 0, stream>>>(cntT, posT, bsums, FLAT);
  k_scan2<<<1, 256, 0, stream>>>(bsums, gF);
  k_scan3<<<gF, 256, 0, stream>>>(posT, bsums, FLAT, E);
  k_bin_scatter<<<NBLK, 256, 0, stream>>>(esrc, edst, posT, binned, E, CH, NBLK, NB);
  k_bucket_csr<<<NB, 256, 0, stream>>>(binned, posT, ssrc, offs, N, NBLK, NB, E);

  int gSp = (N + 3) / 4;
  // layer 1
  k_gemm<<<640, 256, 0, stream>>>(x, W1, as1, ad1, hgb, als, ald, N);
  k_spmm<<<gSp, 256, 0, stream>>>(offs, ssrc, hgb, als, ald, b1, A, N);
  // layer 2
  k_gemm<<<640, 256, 0, stream>>>(A, W2, as2, ad2, hgb, als, ald, N);
  k_spmm<<<gSp, 256, 0, stream>>>(offs, ssrc, hgb, als, ald, b2, A, N);
  // readout
  int NG = N / 20;
  k_final<<<(NG + 3) / 4, 256, 0, stream>>>(A, Wo, bo, out, NG);
}

// Round 5
// 430.930 us; speedup vs baseline: 1.3276x; 1.2180x over previous
//
#include <hip/hip_runtime.h>
#include <math.h>

#define F 64
#define NPB 160        // nodes per bucket
#define STAGE_CAP 6304 // staged CSR entries per bucket (mean ~2720, +60 sigma)

// ---------------- bucketed CSR build ----------------

__global__ __launch_bounds__(256) void k_bin_count(const int* __restrict__ edst, int* __restrict__ cntT,
                                                   int e, int ch, int nblk, int nb) {
  __shared__ int h[1024];
  int k = blockIdx.x, tid = threadIdx.x;
  for (int i = tid; i < nb; i += 256) h[i] = 0;
  __syncthreads();
  int beg = k * ch, end = min(e, beg + ch);
  for (int i = beg + tid; i < end; i += 256) atomicAdd(&h[edst[i] / NPB], 1);
  __syncthreads();
  for (int b = tid; b < nb; b += 256) cntT[b * nblk + k] = h[b];
}

__global__ __launch_bounds__(256) void k_scan1(const int* __restrict__ counts, int* __restrict__ offs,
                                               int* __restrict__ bsums, int n) {
  int tid = threadIdx.x, lane = tid & 63, wv = tid >> 6;
  int i = blockIdx.x * 256 + tid;
  int v = (i < n) ? counts[i] : 0;
  int x = v;
  #pragma unroll
  for (int o = 1; o <= 32; o <<= 1) { int y = __shfl_up(x, o); if (lane >= o) x += y; }
  __shared__ int wsum[4];
  if (lane == 63) wsum[wv] = x;
  __syncthreads();
  int add = 0;
  for (int w = 0; w < wv; w++) add += wsum[w];
  int incl = x + add;
  if (i < n) offs[i] = incl - v;
  if (tid == 255) bsums[blockIdx.x] = incl;
}

__global__ __launch_bounds__(256) void k_scan2(int* __restrict__ bs, int nb) {
  __shared__ int wsum[4];
  __shared__ int carry_sh;
  int tid = threadIdx.x, lane = tid & 63, wv = tid >> 6;
  if (tid == 0) carry_sh = 0;
  __syncthreads();
  for (int base = 0; base < nb; base += 256) {
    int i = base + tid;
    int v = (i < nb) ? bs[i] : 0;
    int x = v;
    #pragma unroll
    for (int o = 1; o <= 32; o <<= 1) { int y = __shfl_up(x, o); if (lane >= o) x += y; }
    if (lane == 63) wsum[wv] = x;
    __syncthreads();
    int add = 0;
    for (int w = 0; w < wv; w++) add += wsum[w];
    int incl = x + add;
    int carry = carry_sh;
    if (i < nb) bs[i] = incl - v + carry;
    __syncthreads();
    if (tid == 255) carry_sh = carry + incl;
    __syncthreads();
  }
}

__global__ __launch_bounds__(256) void k_scan3(int* __restrict__ offs, const int* __restrict__ bsums,
                                               int n, int total) {
  int i = blockIdx.x * 256 + threadIdx.x;
  if (i < n) offs[i] += bsums[i >> 8];
  if (i == 0) offs[n] = total;
}

__global__ __launch_bounds__(256) void k_bin_scatter(const int* __restrict__ esrc, const int* __restrict__ edst,
                                                     const int* __restrict__ posT, unsigned int* __restrict__ binned,
                                                     int e, int ch, int nblk, int nb) {
  __shared__ int cur[1024];
  int k = blockIdx.x, tid = threadIdx.x;
  for (int b = tid; b < nb; b += 256) cur[b] = posT[b * nblk + k];
  __syncthreads();
  int beg = k * ch, end = min(e, beg + ch);
  for (int i = beg + tid; i < end; i += 256) {
    int d = edst[i];
    int b = d / NPB;
    unsigned int ld = (unsigned int)(d - b * NPB);
    int p = atomicAdd(&cur[b], 1);
    binned[p] = (unsigned int)esrc[i] | (ld << 24);
  }
}

// one block per bucket: build CSR rows (self-loop at row head), emit ssrc + offs
__global__ __launch_bounds__(256) void k_bucket_csr(const unsigned int* __restrict__ binned,
                                                    const int* __restrict__ posT,
                                                    int* __restrict__ ssrc, int* __restrict__ offs,
                                                    int n, int nblk, int nb, int e) {
  __shared__ int ncnt[NPB];
  __shared__ int noff[NPB];
  __shared__ int cur[NPB];
  __shared__ int sc[256];
  __shared__ int stage[STAGE_CAP];
  int b = blockIdx.x, tid = threadIdx.x;
  int node0 = b * NPB;
  int nn = min(NPB, n - node0);
  int ebeg = posT[b * nblk];
  int eend = posT[(b + 1) * nblk];
  int ecnt = eend - ebeg;
  for (int i = tid; i < NPB; i += 256) ncnt[i] = 0;
  __syncthreads();
  for (int i = tid; i < ecnt; i += 256) { unsigned int v = binned[ebeg + i]; atomicAdd(&ncnt[v >> 24], 1); }
  __syncthreads();
  int x = (tid < nn) ? ncnt[tid] + 1 : 0;
  sc[tid] = x;
  __syncthreads();
  #pragma unroll
  for (int o = 1; o < 256; o <<= 1) {
    int y = (tid >= o) ? sc[tid - o] : 0;
    __syncthreads();
    sc[tid] += y;
    __syncthreads();
  }
  if (tid < nn) noff[tid] = sc[tid] - x;
  __syncthreads();
  int tot = ecnt + nn;
  int outbase = ebeg + node0;
  bool staged = (tot <= STAGE_CAP);
  if (tid < nn) {
    cur[tid] = noff[tid] + 1;
    offs[node0 + tid] = outbase + noff[tid];
    if (staged) stage[noff[tid]] = node0 + tid;
    else        ssrc[outbase + noff[tid]] = node0 + tid;
  }
  __syncthreads();
  if (staged) {
    for (int i = tid; i < ecnt; i += 256) {
      unsigned int v = binned[ebeg + i];
      int p = atomicAdd(&cur[v >> 24], 1);
      stage[p] = (int)(v & 0xFFFFFFu);
    }
    __syncthreads();
    for (int i = tid; i < tot; i += 256) ssrc[outbase + i] = stage[i];
  } else {
    for (int i = tid; i < ecnt; i += 256) {
      unsigned int v = binned[ebeg + i];
      int p = atomicAdd(&cur[v >> 24], 1);
      ssrc[outbase + p] = (int)(v & 0xFFFFFFu);
    }
  }
  if (b == 0 && tid == 0) offs[n] = e + n;
}

// ---------------- GEMM h = in @ W (64x64): bf16 h out, fp32 al_src/al_dst ----------------
__global__ __launch_bounds__(256) void k_gemm(const float* __restrict__ in, const float* __restrict__ W,
                                              const float* __restrict__ avs, const float* __restrict__ avd,
                                              unsigned short* __restrict__ hgb, float* __restrict__ als,
                                              float* __restrict__ ald, int n) {
  __shared__ float4 Xsh[64 * 16];
  int tid = threadIdx.x, lane = tid & 63, wv = tid >> 6;
  float wreg[F];
  #pragma unroll
  for (int k = 0; k < F; k++) wreg[k] = W[k * F + lane];
  float as = avs[lane], ad = avd[lane];
  const float4* in4 = (const float4*)in;
  int nchunks = n >> 6;
  for (int chunk = blockIdx.x; chunk < nchunks; chunk += gridDim.x) {
    int r0 = chunk << 6;
    __syncthreads();
    #pragma unroll
    for (int i = 0; i < 4; i++) Xsh[i * 256 + tid] = in4[(size_t)r0 * 16 + i * 256 + tid];
    __syncthreads();
    int rl0 = wv * 16;
    for (int rl = rl0; rl < rl0 + 16; rl++) {
      float acc = 0.f;
      #pragma unroll
      for (int k4 = 0; k4 < 16; k4++) {
        float4 xk = Xsh[rl * 16 + k4];
        acc = fmaf(xk.x, wreg[k4 * 4 + 0], acc);
        acc = fmaf(xk.y, wreg[k4 * 4 + 1], acc);
        acc = fmaf(xk.z, wreg[k4 * 4 + 2], acc);
        acc = fmaf(xk.w, wreg[k4 * 4 + 3], acc);
      }
      int r = r0 + rl;
      // bf16 round-to-nearest-even
      unsigned int u = __float_as_uint(acc);
      u += 0x7fffu + ((u >> 16) & 1u);
      hgb[(size_t)r * F + lane] = (unsigned short)(u >> 16);
      float ps = acc * as, pd = acc * ad;
      #pragma unroll
      for (int o = 32; o >= 1; o >>= 1) { ps += __shfl_xor(ps, o); pd += __shfl_xor(pd, o); }
      if (lane == 0) { als[r] = ps; ald[r] = pd; }
    }
  }
}

// ---------------- fused softmax+SpMM, two-phase per wave ----------------
// Phase A: edge-parallel (64 lanes): coalesced ssrc, 64-wide als gather, one v_exp; stage (src,ex) in LDS.
// Phase B: 8 groups x 8 lanes x uint4(8 bf16): 8 edges/iteration, 16B/lane gather, fp32 FMA.
__global__ __launch_bounds__(256) void k_spmm(const int* __restrict__ offs, const int* __restrict__ ssrc,
                                              const unsigned short* __restrict__ hgb,
                                              const float* __restrict__ als, const float* __restrict__ ald,
                                              const float* __restrict__ bias, float* __restrict__ outp, int n) {
  __shared__ int2 exsh[4][64];
  int tid = threadIdx.x, lane = tid & 63, wv = tid >> 6;
  int g8 = lane >> 3, l8 = lane & 7;
  const uint4* hg4 = (const uint4*)hgb;
  float bch[8];
  #pragma unroll
  for (int k = 0; k < 8; k++) bch[k] = bias[l8 * 8 + k];
  int nwaves = gridDim.x * 4;
  for (int node = blockIdx.x * 4 + wv; node < n; node += nwaves) {
    int beg = offs[node], end = offs[node + 1];
    int deg = end - beg;
    float aldv = ald[node];
    float s = 0.f;
    float acc[8];
    #pragma unroll
    for (int k = 0; k < 8; k++) acc[k] = 0.f;
    for (int c0 = 0; c0 < deg; c0 += 64) {
      int nv = min(64, deg - c0);
      // phase A (no barrier: same-wave DS ordering)
      if (lane < nv) {
        int src = ssrc[beg + c0 + lane];
        float t = als[src] + aldv;
        t = (t >= 0.f) ? t : 0.2f * t;     // leaky_relu 0.2
        float ex = __expf(t);
        s += ex;
        exsh[wv][lane] = make_int2(src, __float_as_int(ex));
      }
      // phase B: full iterations (no predication)
      int full = nv >> 3;
      #pragma unroll 2
      for (int j8 = 0; j8 < full; j8++) {
        int2 pv = exsh[wv][(j8 << 3) + g8];
        float w = __int_as_float(pv.y);
        uint4 u = hg4[(size_t)pv.x * 8 + l8];
        acc[0] = fmaf(w, __uint_as_float(u.x << 16), acc[0]);
        acc[1] = fmaf(w, __uint_as_float(u.x & 0xffff0000u), acc[1]);
        acc[2] = fmaf(w, __uint_as_float(u.y << 16), acc[2]);
        acc[3] = fmaf(w, __uint_as_float(u.y & 0xffff0000u), acc[3]);
        acc[4] = fmaf(w, __uint_as_float(u.z << 16), acc[4]);
        acc[5] = fmaf(w, __uint_as_float(u.z & 0xffff0000u), acc[5]);
        acc[6] = fmaf(w, __uint_as_float(u.w << 16), acc[6]);
        acc[7] = fmaf(w, __uint_as_float(u.w & 0xffff0000u), acc[7]);
      }
      int rem = nv & 7;
      if (rem) {
        bool valid = g8 < rem;
        int2 pv = exsh[wv][valid ? (full << 3) + g8 : 0];
        float w = valid ? __int_as_float(pv.y) : 0.f;
        uint4 u = hg4[(size_t)pv.x * 8 + l8];
        acc[0] = fmaf(w, __uint_as_float(u.x << 16), acc[0]);
        acc[1] = fmaf(w, __uint_as_float(u.x & 0xffff0000u), acc[1]);
        acc[2] = fmaf(w, __uint_as_float(u.y << 16), acc[2]);
        acc[3] = fmaf(w, __uint_as_float(u.y & 0xffff0000u), acc[3]);
        acc[4] = fmaf(w, __uint_as_float(u.z << 16), acc[4]);
        acc[5] = fmaf(w, __uint_as_float(u.z & 0xffff0000u), acc[5]);
        acc[6] = fmaf(w, __uint_as_float(u.w << 16), acc[6]);
        acc[7] = fmaf(w, __uint_as_float(u.w & 0xffff0000u), acc[7]);
      }
    }
    #pragma unroll
    for (int o = 1; o <= 32; o <<= 1) s += __shfl_xor(s, o);
    #pragma unroll
    for (int o = 8; o <= 32; o <<= 1) {
      #pragma unroll
      for (int k = 0; k < 8; k++) acc[k] += __shfl_xor(acc[k], o);
    }
    if (g8 == 0) {
      float iv = 1.f / (s + 1e-16f);
      float4 r0, r1;
      r0.x = fmaxf(fmaf(acc[0], iv, bch[0]), 0.f);
      r0.y = fmaxf(fmaf(acc[1], iv, bch[1]), 0.f);
      r0.z = fmaxf(fmaf(acc[2], iv, bch[2]), 0.f);
      r0.w = fmaxf(fmaf(acc[3], iv, bch[3]), 0.f);
      r1.x = fmaxf(fmaf(acc[4], iv, bch[4]), 0.f);
      r1.y = fmaxf(fmaf(acc[5], iv, bch[5]), 0.f);
      r1.z = fmaxf(fmaf(acc[6], iv, bch[6]), 0.f);
      r1.w = fmaxf(fmaf(acc[7], iv, bch[7]), 0.f);
      float4* o4 = (float4*)outp + (size_t)node * 16 + l8 * 2;
      o4[0] = r0;
      o4[1] = r1;
    }
  }
}

// ---------------- final readout ----------------
__global__ __launch_bounds__(256) void k_final(const float* __restrict__ h, const float* __restrict__ Wout,
                                               const float* __restrict__ bout, float* __restrict__ out,
                                               int ng) {
  int tid = threadIdx.x, lane = tid & 63, wv = tid >> 6;
  int g = blockIdx.x * 4 + wv;
  if (g >= ng) return;
  const float4* h4 = (const float4*)h + (size_t)g * 320;
  const float4* w4 = (const float4*)Wout;
  float sacc = 0.f;
  #pragma unroll
  for (int k = 0; k < 5; k++) {
    float4 a = h4[k * 64 + lane];
    float4 b = w4[k * 64 + lane];
    sacc += a.x * b.x + a.y * b.y + a.z * b.z + a.w * b.w;
  }
  #pragma unroll
  for (int o = 32; o >= 1; o >>= 1) sacc += __shfl_xor(sacc, o);
  if (lane == 0) out[g] = sacc + bout[0];
}

// ---------------- launch ----------------
extern "C" void kernel_launch(void* const* d_in, const int* in_sizes, int n_in,
                              void* d_out, int out_size, void* d_ws, size_t ws_size,
                              hipStream_t stream) {
  const float* x   = (const float*)d_in[0];
  const int*   ei  = (const int*)d_in[1];
  const float* W1  = (const float*)d_in[2];
  const float* as1 = (const float*)d_in[3];
  const float* ad1 = (const float*)d_in[4];
  const float* b1  = (const float*)d_in[5];
  const float* W2  = (const float*)d_in[6];
  const float* as2 = (const float*)d_in[7];
  const float* ad2 = (const float*)d_in[8];
  const float* b2  = (const float*)d_in[9];
  const float* Wo  = (const float*)d_in[10];
  const float* bo  = (const float*)d_in[11];
  float* out = (float*)d_out;

  const int N = in_sizes[0] / F;
  const int E = in_sizes[1] / 2;
  const int* esrc = ei;
  const int* edst = ei + E;

  size_t off = 0;
  auto alloc = [&](size_t bytes) -> void* {
    void* p = (char*)d_ws + off;
    off += (bytes + 255) & ~(size_t)255;
    return p;
  };
  float* A    = (float*)alloc((size_t)N * F * 4);           // agg outputs (fp32); CSR cnt/pos scratch aliases head
  unsigned short* hgb = (unsigned short*)alloc((size_t)N * F * 2);  // bf16 gemm outputs; binned aliases head
  float* als  = (float*)alloc((size_t)N * 4);
  float* ald  = (float*)alloc((size_t)N * 4);
  int* offs   = (int*)alloc((size_t)(N + 1) * 4);
  int* bsums  = (int*)alloc(8192);
  int* ssrc   = (int*)alloc((size_t)(E + N) * 4);           // CSR src lists
  (void)ws_size; (void)n_in; (void)out_size;

  const int NBLK = 160;
  const int NB = (N + NPB - 1) / NPB;
  const int CH = (E + NBLK - 1) / NBLK;
  const int FLAT = NB * NPB > NB * NBLK ? NB * NBLK : NB * NBLK;

  int* cntT = (int*)A;
  int* posT = (int*)((char*)A + ((size_t)NB * NBLK * 4 + 1024));
  unsigned int* binned = (unsigned int*)hgb;   // E uints <= N*F*2 bytes; dead before k_gemm writes hgb

  int gF = (NB * NBLK + 255) / 256;

  // CSR build: bucketed counting sort (dst-major), self-loop at row head
  k_bin_count<<<NBLK, 256, 0, stream>>>(edst, cntT, E, CH, NBLK, NB);
  k_scan1<<<gF, 256, 0, stream>>>(cntT, posT, bsums, NB * NBLK);
  k_scan2<<<1, 256, 0, stream>>>(bsums, gF);
  k_scan3<<<gF, 256, 0, stream>>>(posT, bsums, NB * NBLK, E);
  k_bin_scatter<<<NBLK, 256, 0, stream>>>(esrc, edst, posT, binned, E, CH, NBLK, NB);
  k_bucket_csr<<<NB, 256, 0, stream>>>(binned, posT, ssrc, offs, N, NBLK, NB, E);

  int gSp = 4096;  // persistent-ish: ~10 nodes per wave
  // layer 1
  k_gemm<<<640, 256, 0, stream>>>(x, W1, as1, ad1, hgb, als, ald, N);
  k_spmm<<<gSp, 256, 0, stream>>>(offs, ssrc, hgb, als, ald, b1, A, N);
  // layer 2
  k_gemm<<<640, 256, 0, stream>>>(A, W2, as2, ad2, hgb, als, ald, N);
  k_spmm<<<gSp, 256, 0, stream>>>(offs, ssrc, hgb, als, ald, b2, A, N);
  // readout
  int NG = N / 20;
  k_final<<<(NG + 3) / 4, 256, 0, stream>>>(A, Wo, bo, out, NG);
}